// Round 1
// baseline (12.144 us; speedup 1.0000x reference)
//
#include <hip/hip_runtime.h>

#define N_ROWS 16384
#define D 64

__global__ __launch_bounds__(256) void kl_stage1(const float* __restrict__ loc_g,
                                                 const float* __restrict__ loc_u,
                                                 const float* __restrict__ scl_g,
                                                 const float* __restrict__ scl_u,
                                                 float* __restrict__ partials,
                                                 int n_rows) {
    const int tid = threadIdx.x;
    const int lane = tid & 63;
    const int wave_in_blk = tid >> 6;              // 0..3
    const int waves_per_blk = blockDim.x >> 6;
    const int wave_id = blockIdx.x * waves_per_blk + wave_in_blk;
    const int total_waves = gridDim.x * waves_per_blk;
    const int group = lane >> 4;                   // which of 4 rows this lane works
    const int sub = lane & 15;                     // 16 lanes x float4 = 64 elems/row

    float acc = 0.0f;

    for (int base = wave_id * 4; base < n_rows; base += total_waves * 4) {
        const int row = base + group;
        const int idx4 = row * (D / 4) + sub;      // float4 index; wave reads 1KB/array contiguous
        float4 g4  = reinterpret_cast<const float4*>(loc_g)[idx4];
        float4 sg4 = reinterpret_cast<const float4*>(scl_g)[idx4];
        float4 u4  = reinterpret_cast<const float4*>(loc_u)[idx4];
        float4 su4 = reinterpret_cast<const float4*>(scl_u)[idx4];

        float A = 0.f, Gg = 0.f, G1 = 0.f, P = 0.f, R = 0.f;
        float B = 0.f, Ug = 0.f, U1 = 0.f, Q = 0.f;
        const float* gp  = reinterpret_cast<const float*>(&g4);
        const float* sgp = reinterpret_cast<const float*>(&sg4);
        const float* up  = reinterpret_cast<const float*>(&u4);
        const float* sup = reinterpret_cast<const float*>(&su4);
        #pragma unroll
        for (int e = 0; e < 4; ++e) {
            float g = gp[e], sg = sgp[e], u = up[e], su = sup[e];
            float sg2 = sg * sg, su2 = su * su;
            float g2 = g * g, u2 = u * u;
            float a = 0.5f / sg2;                  // 1/(2*sg^2)
            float b = 0.5f / su2;                  // 1/(2*su^2)
            A  += a;        Gg += g * a;  G1 += g;
            P  += sg2 + g2; R  += g2 * a + u2 * b;
            B  += b;        Ug += u * b;  U1 += u;
            Q  += su2 + u2;
        }

        // reduce 9 partial sums across the 16-lane group (4-step butterfly)
        #pragma unroll
        for (int off = 1; off < 16; off <<= 1) {
            A  += __shfl_xor(A,  off);
            Gg += __shfl_xor(Gg, off);
            G1 += __shfl_xor(G1, off);
            P  += __shfl_xor(P,  off);
            R  += __shfl_xor(R,  off);
            B  += __shfl_xor(B,  off);
            Ug += __shfl_xor(Ug, off);
            U1 += __shfl_xor(U1, off);
            Q  += __shfl_xor(Q,  off);
        }

        // per-row pairwise sum S_n = A*Q + B*P + 64*R - 2*(Gg*U1 + G1*Ug)
        float S = A * Q + B * P + 64.0f * R - 2.0f * (Gg * U1 + G1 * Ug);
        // sum S across the 4 groups (rows) of the wave
        S += __shfl_xor(S, 16);
        S += __shfl_xor(S, 32);
        acc += S;
    }

    __shared__ float lds[8];
    if (lane == 0) lds[wave_in_blk] = acc;
    __syncthreads();
    if (tid == 0) {
        float s = 0.f;
        for (int w = 0; w < waves_per_blk; ++w) s += lds[w];
        partials[blockIdx.x] = s;
    }
}

__global__ void kl_stage2(const float* __restrict__ partials, int nb,
                          float* __restrict__ out) {
    double s = 0.0;
    for (int i = threadIdx.x; i < nb; i += 64) s += (double)partials[i];
    #pragma unroll
    for (int off = 1; off < 64; off <<= 1) s += __shfl_xor(s, off);
    if (threadIdx.x == 0) {
        double mean = 0.5 * (s / ((double)N_ROWS * 64.0 * 64.0)) - 0.5;
        out[0] = (float)mean;
    }
}

extern "C" void kernel_launch(void* const* d_in, const int* in_sizes, int n_in,
                              void* d_out, int out_size, void* d_ws, size_t ws_size,
                              hipStream_t stream) {
    const float* loc_g = (const float*)d_in[0];   // z_loc_gs   [N,64]
    const float* loc_u = (const float*)d_in[1];   // z_loc_uns  [N,64]
    const float* scl_g = (const float*)d_in[2];   // z_scale_gs [N,64]
    const float* scl_u = (const float*)d_in[3];   // z_scale_uns[N,64]
    float* out = (float*)d_out;
    float* partials = (float*)d_ws;

    const int NB = 256;   // 256 blocks x 4 waves = 1024 waves; 4 chunks of 4 rows each
    kl_stage1<<<NB, 256, 0, stream>>>(loc_g, loc_u, scl_g, scl_u, partials, N_ROWS);
    kl_stage2<<<1, 64, 0, stream>>>(partials, NB, out);
}